// Round 10
// baseline (391.171 us; speedup 1.0000x reference)
//
#include <hip/hip_runtime.h>
#include <math.h>

#define N_NODES 100000
#define N_EDGES 1700000
#define F0 256
#define F1 128
#define F2 64
#define NCLS 200
#define NFPAD 208
#define CAP 64

// histogram role geometry
#define NRANGE 64
#define NSPLIT 4
#define HRANGE 1563            // ceil(100000/64); 64*1563 = 100032 >= N_NODES
#define ESPL (N_EDGES / NSPLIT)  // 425000 (divisible by 4)

typedef short bf16x8 __attribute__((ext_vector_type(8)));
typedef float f32x4 __attribute__((ext_vector_type(4)));

__device__ __forceinline__ unsigned short f2bf(float f) {
  unsigned u = __float_as_uint(f);
  return (unsigned short)((u + 0x7FFFu + ((u >> 16) & 1u)) >> 16);
}
__device__ __forceinline__ float bflo(unsigned u) { return __uint_as_float(u << 16); }
__device__ __forceinline__ float bfhi(unsigned u) { return __uint_as_float(u & 0xFFFF0000u); }

__global__ __launch_bounds__(256) void k_dinv(const unsigned* __restrict__ cs4,
                                              const unsigned* __restrict__ cnt,
                                              float* __restrict__ dsrc,
                                              float* __restrict__ ddst) {
  int i = blockIdx.x * 256 + threadIdx.x;
  if (i < N_NODES) {
    unsigned c = cs4[i] + cs4[N_NODES + i] + cs4[2 * N_NODES + i] + cs4[3 * N_NODES + i];
    dsrc[i] = rsqrtf((float)max(c, 1u));
    ddst[i] = rsqrtf((float)max(cnt[i], 1u));
  }
}

// ---------------- weight transpose+cast: Wt[n][k] = bf16(W[k][n]) ----------------
__global__ __launch_bounds__(256) void k_castw(const float* __restrict__ W,
                                               unsigned short* __restrict__ Wt,
                                               int K, int N) {
  int idx = blockIdx.x * 256 + threadIdx.x;
  if (idx < K * N) {
    int n = idx / K, k = idx % K;
    Wt[idx] = f2bf(W[(size_t)k * N + n]);
  }
}

// Wf^T zero-padded to [208][64]
__global__ __launch_bounds__(256) void k_castwf(const float* __restrict__ Wf,
                                                unsigned short* __restrict__ Wfp) {
  int idx = blockIdx.x * 256 + threadIdx.x;
  if (idx < NFPAD * F2) {
    int n = idx / F2, k = idx % F2;
    Wfp[idx] = (n < NCLS) ? f2bf(Wf[(size_t)k * NCLS + n]) : (unsigned short)0;
  }
}

// ---------------- FUSED: bucket-fill + src-histogram + gemm1 ----------------
// fill role: p=atomicAdd(cnt[d]); bucket[d*CAP+p]=src[e].            (atomic-fabric)
// hist role: LDS histogram of src over (node-range, edge-split);
//            plain-writes partials to cs4[split][node] -- NO atomics. (L3 streaming)
// gemm role: h1 = bf16(x @ W1) unscaled.                             (MFMA)
__global__ __launch_bounds__(256) void k_fill_gemm1(const int* __restrict__ src,
                                                    const int* __restrict__ dst,
                                                    unsigned* __restrict__ cs4,
                                                    unsigned* __restrict__ cnt,
                                                    int* __restrict__ bucket,
                                                    const float* __restrict__ X,
                                                    const unsigned short* __restrict__ Wt,
                                                    unsigned short* __restrict__ out) {
  constexpr int BM = 128;
  constexpr int BK = 64;
  constexpr int LDR = BK + 8;
  constexpr int NB_GEMM = (N_NODES + BM - 1) / BM;   // 782
  constexpr int NB_HIST = NRANGE * NSPLIT;           // 256
  constexpr int NB_CMP = NB_GEMM + NB_HIST;          // 1038
  constexpr int NB_FILL = 2048;
  constexpr int TOT = NB_CMP + NB_FILL;              // 3086

  __shared__ unsigned short as[BM][LDR];
  __shared__ unsigned short bs[F1][LDR];

  const int bid = blockIdx.x;
  const int c0 = (int)(((long long)bid * NB_CMP) / TOT);
  const int c1 = (int)(((long long)(bid + 1) * NB_CMP) / TOT);

  if (c1 > c0) {
    if (c0 < NB_HIST) {
      // ===== HIST role =====
      const int rid = c0 >> 2;        // node range
      const int sid = c0 & 3;         // edge split
      const int rbase = rid * HRANGE;
      unsigned* hls = (unsigned*)as;  // 1563 u32 = 6.25 KB, aliases gemm LDS
      for (int i = threadIdx.x; i < HRANGE; i += 256) hls[i] = 0u;
      __syncthreads();
      const int4* s4 = (const int4*)src;
      const int i1 = (sid + 1) * (ESPL / 4);
      for (int i = sid * (ESPL / 4) + threadIdx.x; i < i1; i += 256) {
        int4 v = s4[i];
        unsigned r;
        r = (unsigned)(v.x - rbase); if (r < HRANGE) atomicAdd(&hls[r], 1u);
        r = (unsigned)(v.y - rbase); if (r < HRANGE) atomicAdd(&hls[r], 1u);
        r = (unsigned)(v.z - rbase); if (r < HRANGE) atomicAdd(&hls[r], 1u);
        r = (unsigned)(v.w - rbase); if (r < HRANGE) atomicAdd(&hls[r], 1u);
      }
      __syncthreads();
      for (int i = threadIdx.x; i < HRANGE; i += 256) {
        int n = rbase + i;
        if (n < N_NODES) cs4[(size_t)sid * N_NODES + n] = hls[i];
      }
    } else {
      // ===== GEMM role =====
      const int g = c0 - NB_HIST;
      const int tid = threadIdx.x;
      const int lane = tid & 63;
      const int wid = tid >> 6;
      const int wr = wid >> 1;
      const int wc = wid & 1;
      const int row0 = wr * 64;
      const int col0 = wc * 64;
      const int fq = lane >> 4;
      const int fr = lane & 15;
      const int brow0 = g * BM;

      f32x4 acc[4][4];
#pragma unroll
      for (int m = 0; m < 4; ++m)
#pragma unroll
        for (int n = 0; n < 4; ++n) acc[m][n] = (f32x4)(0.f);

      for (int k0 = 0; k0 < F0; k0 += BK) {
        __syncthreads();
        for (int chunk = tid; chunk < BM * (BK / 8); chunk += 256) {
          int r = chunk >> 3, c = chunk & 7;
          int gr = brow0 + r;
          float4 v0 = make_float4(0.f, 0.f, 0.f, 0.f), v1 = v0;
          if (gr < N_NODES) {
            const float* p = X + (size_t)gr * F0 + k0 + c * 8;
            v0 = *(const float4*)p;
            v1 = *(const float4*)(p + 4);
          }
          bf16x8 o;
          o[0] = (short)f2bf(v0.x); o[1] = (short)f2bf(v0.y);
          o[2] = (short)f2bf(v0.z); o[3] = (short)f2bf(v0.w);
          o[4] = (short)f2bf(v1.x); o[5] = (short)f2bf(v1.y);
          o[6] = (short)f2bf(v1.z); o[7] = (short)f2bf(v1.w);
          *(bf16x8*)&as[r][c * 8] = o;
        }
        for (int chunk = tid; chunk < F1 * (BK / 8); chunk += 256) {
          int r = chunk >> 3, c = chunk & 7;
          *(uint4*)&bs[r][c * 8] = *(const uint4*)(Wt + (size_t)r * F0 + k0 + c * 8);
        }
        __syncthreads();
#pragma unroll
        for (int ks = 0; ks < 2; ++ks) {
          bf16x8 af[4], bfv[4];
#pragma unroll
          for (int m = 0; m < 4; ++m)
            af[m] = *(const bf16x8*)&as[row0 + m * 16 + fr][ks * 32 + fq * 8];
#pragma unroll
          for (int n = 0; n < 4; ++n)
            bfv[n] = *(const bf16x8*)&bs[col0 + n * 16 + fr][ks * 32 + fq * 8];
#pragma unroll
          for (int m = 0; m < 4; ++m)
#pragma unroll
            for (int n = 0; n < 4; ++n)
              acc[m][n] = __builtin_amdgcn_mfma_f32_16x16x32_bf16(af[m], bfv[n], acc[m][n], 0, 0, 0);
        }
      }
#pragma unroll
      for (int m = 0; m < 4; ++m) {
#pragma unroll
        for (int j = 0; j < 4; ++j) {
          int grow = brow0 + row0 + m * 16 + fq * 4 + j;
          if (grow < N_NODES) {
#pragma unroll
            for (int n = 0; n < 4; ++n) {
              int col = col0 + n * 16 + fr;
              out[(size_t)grow * F1 + col] = f2bf(acc[m][n][j]);
            }
          }
        }
      }
    }
  } else {
    // ===== FILL role: 1 atomic + 1 scattered write per edge =====
    const int fb = bid - c0;
    int i = fb * 256 + threadIdx.x;
    for (int e = i; e < N_EDGES; e += NB_FILL * 256) {
      int s = src[e], d = dst[e];
      unsigned p = atomicAdd(&cnt[d], 1u);
      if (p < CAP) bucket[d * CAP + p] = s;
    }
  }
}

// ---------------- MFMA GEMM (layer 2): out[r,:] = bf16((X[r,:] @ W) * scale[r]) ----------------
template <int K, int BN>
__global__ void k_gemm_mfma(const unsigned short* __restrict__ X,
                            const unsigned short* __restrict__ Wt,
                            const float* __restrict__ scale,
                            unsigned short* __restrict__ out) {
  constexpr int BM = 128;
  constexpr int BK = 64;
  constexpr int LDR = BK + 8;
  constexpr int NWAVE = 2 * (BN / 64);
  constexpr int NTHR = NWAVE * 64;
  __shared__ unsigned short as[BM][LDR];
  __shared__ unsigned short bs[BN][LDR];

  const int tid = threadIdx.x;
  const int lane = tid & 63;
  const int wid = tid >> 6;
  constexpr int WCOLS = BN / 64;
  const int wr = wid / WCOLS;
  const int wc = wid % WCOLS;
  const int row0 = wr * 64;
  const int col0 = wc * 64;
  const int fq = lane >> 4;
  const int fr = lane & 15;
  const int brow0 = blockIdx.x * BM;

  f32x4 acc[4][4];
#pragma unroll
  for (int m = 0; m < 4; ++m)
#pragma unroll
    for (int n = 0; n < 4; ++n) acc[m][n] = (f32x4)(0.f);

  for (int k0 = 0; k0 < K; k0 += BK) {
    __syncthreads();
    for (int chunk = tid; chunk < BM * (BK / 8); chunk += NTHR) {
      int r = chunk >> 3, c = chunk & 7;
      int gr = brow0 + r;
      uint4 v = make_uint4(0u, 0u, 0u, 0u);
      if (gr < N_NODES) v = *(const uint4*)(X + (size_t)gr * K + k0 + c * 8);
      *(uint4*)&as[r][c * 8] = v;
    }
    for (int chunk = tid; chunk < BN * (BK / 8); chunk += NTHR) {
      int r = chunk >> 3, c = chunk & 7;
      *(uint4*)&bs[r][c * 8] = *(const uint4*)(Wt + (size_t)r * K + k0 + c * 8);
    }
    __syncthreads();
#pragma unroll
    for (int ks = 0; ks < 2; ++ks) {
      bf16x8 af[4], bfv[4];
#pragma unroll
      for (int m = 0; m < 4; ++m)
        af[m] = *(const bf16x8*)&as[row0 + m * 16 + fr][ks * 32 + fq * 8];
#pragma unroll
      for (int n = 0; n < 4; ++n)
        bfv[n] = *(const bf16x8*)&bs[col0 + n * 16 + fr][ks * 32 + fq * 8];
#pragma unroll
      for (int m = 0; m < 4; ++m)
#pragma unroll
        for (int n = 0; n < 4; ++n)
          acc[m][n] = __builtin_amdgcn_mfma_f32_16x16x32_bf16(af[m], bfv[n], acc[m][n], 0, 0, 0);
    }
  }

#pragma unroll
  for (int m = 0; m < 4; ++m) {
#pragma unroll
    for (int j = 0; j < 4; ++j) {
      int grow = brow0 + row0 + m * 16 + fq * 4 + j;
      if (grow < N_NODES) {
        float sc = scale[grow];
#pragma unroll
        for (int n = 0; n < 4; ++n) {
          int col = col0 + n * 16 + fr;
          out[(size_t)grow * BN + col] = f2bf(acc[m][n][j] * sc);
        }
      }
    }
  }
}

// ---------------- gather F=128 bf16: per-edge dsrc scale fused in ----------------
__global__ __launch_bounds__(256) void k_gather128(const int* __restrict__ bucket,
                                                   const unsigned* __restrict__ cnt,
                                                   const unsigned short* __restrict__ h,
                                                   const float* __restrict__ dsrc,
                                                   const float* __restrict__ ddst,
                                                   const float* __restrict__ b,
                                                   unsigned short* __restrict__ out) {
  const int lane = threadIdx.x & 63;
  const int node = blockIdx.x * 4 + (threadIdx.x >> 6);
  if (node >= N_NODES) return;
  const unsigned deg = min(cnt[node], (unsigned)CAP);
  const int* bp = bucket + (size_t)node * CAP;
  const unsigned* hp = (const unsigned*)h;  // 64 uints per row
  float a0 = 0.f, a1 = 0.f;
  unsigned j = 0;
  for (; j + 4 <= deg; j += 4) {
    int s0 = bp[j + 0], s1 = bp[j + 1], s2 = bp[j + 2], s3 = bp[j + 3];
    float d0 = dsrc[s0], d1 = dsrc[s1], d2 = dsrc[s2], d3 = dsrc[s3];
    unsigned u0 = hp[(size_t)s0 * 64 + lane];
    unsigned u1 = hp[(size_t)s1 * 64 + lane];
    unsigned u2 = hp[(size_t)s2 * 64 + lane];
    unsigned u3 = hp[(size_t)s3 * 64 + lane];
    a0 += d0 * bflo(u0) + d1 * bflo(u1) + d2 * bflo(u2) + d3 * bflo(u3);
    a1 += d0 * bfhi(u0) + d1 * bfhi(u1) + d2 * bfhi(u2) + d3 * bfhi(u3);
  }
  for (; j < deg; ++j) {
    int s = bp[j];
    float ds = dsrc[s];
    unsigned u = hp[(size_t)s * 64 + lane];
    a0 += ds * bflo(u);
    a1 += ds * bfhi(u);
  }
  float dd = ddst[node];
  float2 bb = *(const float2*)(b + lane * 2);
  float v0 = fmaxf(a0 * dd + bb.x, 0.f);
  float v1 = fmaxf(a1 * dd + bb.y, 0.f);
  unsigned o = (unsigned)f2bf(v0) | ((unsigned)f2bf(v1) << 16);
  ((unsigned*)out)[(size_t)node * 64 + lane] = o;
}

// ---------------- gather F=64 bf16 -> bf16 (h already dsrc-scaled) ----------------
__global__ __launch_bounds__(256) void k_gather64(const int* __restrict__ bucket,
                                                  const unsigned* __restrict__ cnt,
                                                  const unsigned short* __restrict__ h,
                                                  const float* __restrict__ ddst,
                                                  const float* __restrict__ b,
                                                  unsigned short* __restrict__ out) {
  const int lane = threadIdx.x & 63;
  const int node = blockIdx.x * 4 + (threadIdx.x >> 6);
  if (node >= N_NODES) return;
  const int half = lane >> 5;
  const int fl = lane & 31;
  const unsigned deg = min(cnt[node], (unsigned)CAP);
  const int* bp = bucket + (size_t)node * CAP;
  const unsigned* hp = (const unsigned*)h;  // 32 uints per row
  float a0 = 0.f, a1 = 0.f;
  unsigned j = half;
  for (; j + 2 < deg; j += 4) {
    int s0 = bp[j], s1 = bp[j + 2];
    unsigned u0 = hp[(size_t)s0 * 32 + fl];
    unsigned u1 = hp[(size_t)s1 * 32 + fl];
    a0 += bflo(u0) + bflo(u1);
    a1 += bfhi(u0) + bfhi(u1);
  }
  if (j < deg) {
    unsigned u = hp[(size_t)bp[j] * 32 + fl];
    a0 += bflo(u);
    a1 += bfhi(u);
  }
  a0 += __shfl_xor(a0, 32);
  a1 += __shfl_xor(a1, 32);
  if (half == 0) {
    float dd = ddst[node];
    float2 bb = *(const float2*)(b + fl * 2);
    float v0 = fmaxf(a0 * dd + bb.x, 0.f);
    float v1 = fmaxf(a1 * dd + bb.y, 0.f);
    unsigned o = (unsigned)f2bf(v0) | ((unsigned)f2bf(v1) << 16);
    ((unsigned*)out)[(size_t)node * 32 + fl] = o;
  }
}

// ---------------- final (MFMA): logits = h @ Wf + bf; out = log_softmax ----------------
__global__ __launch_bounds__(256) void k_final_mfma(const unsigned short* __restrict__ h,
                                                    const unsigned short* __restrict__ Wfp,
                                                    const float* __restrict__ bf,
                                                    float* __restrict__ out) {
  constexpr int BM = 64;
  constexpr int NF = NFPAD / 16;  // 13
  constexpr int LDR = F2 + 8;     // 72
  __shared__ unsigned short as[BM][LDR];
  __shared__ unsigned short bs[NFPAD][LDR];

  const int tid = threadIdx.x;
  const int lane = tid & 63;
  const int wid = tid >> 6;
  const int fq = lane >> 4;
  const int fr = lane & 15;
  const int brow0 = blockIdx.x * BM;

  for (int chunk = tid; chunk < BM * 8; chunk += 256) {
    int r = chunk >> 3, c = chunk & 7;
    int gr = brow0 + r;
    uint4 v = make_uint4(0u, 0u, 0u, 0u);
    if (gr < N_NODES) v = *(const uint4*)(h + (size_t)gr * F2 + c * 8);
    *(uint4*)&as[r][c * 8] = v;
  }
  for (int chunk = tid; chunk < NFPAD * 8; chunk += 256) {
    int r = chunk >> 3, c = chunk & 7;
    *(uint4*)&bs[r][c * 8] = *(const uint4*)(Wfp + (size_t)r * F2 + c * 8);
  }
  __syncthreads();

  f32x4 acc[NF];
#pragma unroll
  for (int n = 0; n < NF; ++n) acc[n] = (f32x4)(0.f);

#pragma unroll
  for (int ks = 0; ks < 2; ++ks) {
    bf16x8 af = *(const bf16x8*)&as[wid * 16 + fr][ks * 32 + fq * 8];
#pragma unroll
    for (int n = 0; n < NF; ++n) {
      bf16x8 bv = *(const bf16x8*)&bs[n * 16 + fr][ks * 32 + fq * 8];
      acc[n] = __builtin_amdgcn_mfma_f32_16x16x32_bf16(af, bv, acc[n], 0, 0, 0);
    }
  }

  const int nval = (fr < NCLS - (NF - 1) * 16) ? NF : NF - 1;
  float bias[NF];
#pragma unroll
  for (int n = 0; n < NF; ++n) {
    int col = n * 16 + fr;
    bias[n] = (col < NCLS) ? bf[col] : 0.f;
  }

#pragma unroll
  for (int j = 0; j < 4; ++j) {
    const int grow = brow0 + wid * 16 + fq * 4 + j;
    float v[NF];
    float m = -1e30f;
#pragma unroll
    for (int n = 0; n < NF; ++n) {
      v[n] = acc[n][j] + bias[n];
      if (n < nval) m = fmaxf(m, v[n]);
    }
#pragma unroll
    for (int o = 1; o < 16; o <<= 1) m = fmaxf(m, __shfl_xor(m, o));
    float s = 0.f;
#pragma unroll
    for (int n = 0; n < NF; ++n)
      if (n < nval) s += expf(v[n] - m);
#pragma unroll
    for (int o = 1; o < 16; o <<= 1) s += __shfl_xor(s, o);
    float ls = logf(s);
    if (grow < N_NODES) {
#pragma unroll
      for (int n = 0; n < NF; ++n)
        if (n < nval) out[(size_t)grow * NCLS + n * 16 + fr] = v[n] - m - ls;
    }
  }
}

extern "C" void kernel_launch(void* const* d_in, const int* in_sizes, int n_in,
                              void* d_out, int out_size, void* d_ws, size_t ws_size,
                              hipStream_t stream) {
  const float* x = (const float*)d_in[0];
  const int* src = (const int*)d_in[1];
  const int* dst = (const int*)d_in[2];
  const float* W1 = (const float*)d_in[3];
  const float* b1 = (const float*)d_in[4];
  const float* W2 = (const float*)d_in[5];
  const float* b2 = (const float*)d_in[6];
  const float* Wf = (const float*)d_in[7];
  const float* bf = (const float*)d_in[8];
  float* out = (float*)d_out;

  // ---- workspace layout (~81 MB), 256B-aligned blocks ----
  char* base = (char*)d_ws;
  size_t off = 0;
  auto alloc = [&](size_t bytes) -> void* {
    off = (off + 255) & ~(size_t)255;
    void* p = base + off;
    off += bytes;
    return p;
  };
  unsigned* cnt = (unsigned*)alloc((size_t)N_NODES * 4);          // in-degree cursor (memset)
  unsigned* cs4 = (unsigned*)alloc(4 * (size_t)N_NODES * 4);      // out-degree partials (fully written by hist)
  float* dsrc = (float*)alloc(N_NODES * 4);
  float* ddst = (float*)alloc(N_NODES * 4);
  int* bucket = (int*)alloc((size_t)N_NODES * CAP * 4);                   // 25.6 MB
  unsigned short* P1 = (unsigned short*)alloc((size_t)N_NODES * F1 * 2);  // h1, then h2
  unsigned short* P2 = (unsigned short*)alloc((size_t)N_NODES * F1 * 2);  // h1f, then agg2
  unsigned short* wt1 = (unsigned short*)alloc((size_t)F1 * F0 * 2);
  unsigned short* wt2 = (unsigned short*)alloc((size_t)F2 * F1 * 2);
  unsigned short* wtf = (unsigned short*)alloc((size_t)NFPAD * F2 * 2);

  unsigned short* h1 = P1;
  unsigned short* h1f = P2;
  unsigned short* h2 = P1;             // aliases h1 (dead after gather128)
  unsigned short* agg2 = P2;           // aliases h1f (dead after gemm2)

  hipMemsetAsync(cnt, 0, (size_t)N_NODES * sizeof(unsigned), stream);

  k_castw<<<(F0 * F1 + 255) / 256, 256, 0, stream>>>(W1, wt1, F0, F1);
  k_castw<<<(F1 * F2 + 255) / 256, 256, 0, stream>>>(W2, wt2, F1, F2);
  k_castwf<<<(NFPAD * F2 + 255) / 256, 256, 0, stream>>>(Wf, wtf);

  // fused: bucket-fill + src-histogram + layer-1 GEMM
  constexpr int NB_GEMM = (N_NODES + 127) / 128;
  constexpr int NB_HIST = NRANGE * NSPLIT;
  constexpr int NB_FILL = 2048;
  k_fill_gemm1<<<NB_GEMM + NB_HIST + NB_FILL, 256, 0, stream>>>(src, dst, cs4, cnt, bucket, x, wt1, h1);

  k_dinv<<<(N_NODES + 255) / 256, 256, 0, stream>>>(cs4, cnt, dsrc, ddst);

  // layer 1 aggregate (dsrc applied per gathered row)
  k_gather128<<<(N_NODES + 3) / 4, 256, 0, stream>>>(bucket, cnt, h1, dsrc, ddst, b1, h1f);

  // layer 2
  k_gemm_mfma<F1, F2><<<(N_NODES + 127) / 128, 128, 0, stream>>>(h1f, wt2, dsrc, h2);
  k_gather64<<<(N_NODES + 3) / 4, 256, 0, stream>>>(bucket, cnt, h2, ddst, b2, agg2);

  // classifier + log_softmax (MFMA, in-register softmax)
  k_final_mfma<<<(N_NODES + 63) / 64, 256, 0, stream>>>(agg2, wtf, bf, out);
}

// Round 11
// 340.690 us; speedup vs baseline: 1.1482x; 1.1482x over previous
//
#include <hip/hip_runtime.h>
#include <math.h>

#define N_NODES 100000
#define N_EDGES 1700000
#define F0 256
#define F1 128
#define F2 64
#define NCLS 200
#define NFPAD 208
#define CAP 64

typedef short bf16x8 __attribute__((ext_vector_type(8)));
typedef float f32x4 __attribute__((ext_vector_type(4)));

__device__ __forceinline__ unsigned short f2bf(float f) {
  unsigned u = __float_as_uint(f);
  return (unsigned short)((u + 0x7FFFu + ((u >> 16) & 1u)) >> 16);
}
__device__ __forceinline__ float bflo(unsigned u) { return __uint_as_float(u << 16); }
__device__ __forceinline__ float bfhi(unsigned u) { return __uint_as_float(u & 0xFFFF0000u); }

__global__ __launch_bounds__(256) void k_dinv(const unsigned* __restrict__ cs,
                                              const unsigned* __restrict__ cnt,
                                              float* __restrict__ dsrc,
                                              float* __restrict__ ddst) {
  int i = blockIdx.x * 256 + threadIdx.x;
  if (i < N_NODES) {
    dsrc[i] = rsqrtf((float)max(cs[i], 1u));
    ddst[i] = rsqrtf((float)max(cnt[i], 1u));
  }
}

// ---------------- weight transpose+cast: Wt[n][k] = bf16(W[k][n]) ----------------
__global__ __launch_bounds__(256) void k_castw(const float* __restrict__ W,
                                               unsigned short* __restrict__ Wt,
                                               int K, int N) {
  int idx = blockIdx.x * 256 + threadIdx.x;
  if (idx < K * N) {
    int n = idx / K, k = idx % K;
    Wt[idx] = f2bf(W[(size_t)k * N + n]);
  }
}

// Wf^T zero-padded to [208][64]
__global__ __launch_bounds__(256) void k_castwf(const float* __restrict__ Wf,
                                                unsigned short* __restrict__ Wfp) {
  int idx = blockIdx.x * 256 + threadIdx.x;
  if (idx < NFPAD * F2) {
    int n = idx / F2, k = idx % F2;
    Wfp[idx] = (n < NCLS) ? f2bf(Wf[(size_t)k * NCLS + n]) : (unsigned short)0;
  }
}

// ---------------- FUSED: bucket-fill (atomic/latency-bound) + gemm1 (MFMA-bound) ----------------
__global__ __launch_bounds__(256) void k_fill_gemm1(const int* __restrict__ src,
                                                    const int* __restrict__ dst,
                                                    unsigned* __restrict__ cs,
                                                    unsigned* __restrict__ cnt,
                                                    int* __restrict__ bucket,
                                                    const float* __restrict__ X,
                                                    const unsigned short* __restrict__ Wt,
                                                    unsigned short* __restrict__ out) {
  constexpr int BM = 128;
  constexpr int BK = 64;
  constexpr int LDR = BK + 8;
  constexpr int NB_GEMM = (N_NODES + BM - 1) / BM;  // 782
  constexpr int NB_FILL = 2048;
  constexpr int TOT = NB_GEMM + NB_FILL;

  __shared__ unsigned short as[BM][LDR];
  __shared__ unsigned short bs[F1][LDR];

  const int bid = blockIdx.x;
  const int g0 = (int)(((long long)bid * NB_GEMM) / TOT);
  const int g1 = (int)(((long long)(bid + 1) * NB_GEMM) / TOT);

  if (g1 > g0) {
    const int tid = threadIdx.x;
    const int lane = tid & 63;
    const int wid = tid >> 6;
    const int wr = wid >> 1;
    const int wc = wid & 1;
    const int row0 = wr * 64;
    const int col0 = wc * 64;
    const int fq = lane >> 4;
    const int fr = lane & 15;
    const int brow0 = g0 * BM;

    f32x4 acc[4][4];
#pragma unroll
    for (int m = 0; m < 4; ++m)
#pragma unroll
      for (int n = 0; n < 4; ++n) acc[m][n] = (f32x4)(0.f);

    for (int k0 = 0; k0 < F0; k0 += BK) {
      __syncthreads();
      for (int chunk = tid; chunk < BM * (BK / 8); chunk += 256) {
        int r = chunk >> 3, c = chunk & 7;
        int gr = brow0 + r;
        float4 v0 = make_float4(0.f, 0.f, 0.f, 0.f), v1 = v0;
        if (gr < N_NODES) {
          const float* p = X + (size_t)gr * F0 + k0 + c * 8;
          v0 = *(const float4*)p;
          v1 = *(const float4*)(p + 4);
        }
        bf16x8 o;
        o[0] = (short)f2bf(v0.x); o[1] = (short)f2bf(v0.y);
        o[2] = (short)f2bf(v0.z); o[3] = (short)f2bf(v0.w);
        o[4] = (short)f2bf(v1.x); o[5] = (short)f2bf(v1.y);
        o[6] = (short)f2bf(v1.z); o[7] = (short)f2bf(v1.w);
        *(bf16x8*)&as[r][c * 8] = o;
      }
      for (int chunk = tid; chunk < F1 * (BK / 8); chunk += 256) {
        int r = chunk >> 3, c = chunk & 7;
        *(uint4*)&bs[r][c * 8] = *(const uint4*)(Wt + (size_t)r * F0 + k0 + c * 8);
      }
      __syncthreads();
#pragma unroll
      for (int ks = 0; ks < 2; ++ks) {
        bf16x8 af[4], bfv[4];
#pragma unroll
        for (int m = 0; m < 4; ++m)
          af[m] = *(const bf16x8*)&as[row0 + m * 16 + fr][ks * 32 + fq * 8];
#pragma unroll
        for (int n = 0; n < 4; ++n)
          bfv[n] = *(const bf16x8*)&bs[col0 + n * 16 + fr][ks * 32 + fq * 8];
#pragma unroll
        for (int m = 0; m < 4; ++m)
#pragma unroll
          for (int n = 0; n < 4; ++n)
            acc[m][n] = __builtin_amdgcn_mfma_f32_16x16x32_bf16(af[m], bfv[n], acc[m][n], 0, 0, 0);
      }
    }
#pragma unroll
    for (int m = 0; m < 4; ++m) {
#pragma unroll
      for (int j = 0; j < 4; ++j) {
        int grow = brow0 + row0 + m * 16 + fq * 4 + j;
        if (grow < N_NODES) {
#pragma unroll
          for (int n = 0; n < 4; ++n) {
            int col = col0 + n * 16 + fr;
            out[(size_t)grow * F1 + col] = f2bf(acc[m][n][j]);
          }
        }
      }
    }
  } else {
    const int fb = bid - g0;
    int i = fb * 256 + threadIdx.x;
    for (int e = i; e < N_EDGES; e += NB_FILL * 256) {
      int s = src[e], d = dst[e];
      unsigned p = atomicAdd(&cnt[d], 1u);
      if (p < CAP) bucket[d * CAP + p] = s;
      atomicAdd(&cs[s], 1u);
    }
  }
}

// ---------------- MFMA GEMM (layer 2): out[r,:] = bf16((X[r,:] @ W) * scale[r]) ----------------
template <int K, int BN>
__global__ void k_gemm_mfma(const unsigned short* __restrict__ X,
                            const unsigned short* __restrict__ Wt,
                            const float* __restrict__ scale,
                            unsigned short* __restrict__ out) {
  constexpr int BM = 128;
  constexpr int BK = 64;
  constexpr int LDR = BK + 8;
  constexpr int NWAVE = 2 * (BN / 64);
  constexpr int NTHR = NWAVE * 64;
  __shared__ unsigned short as[BM][LDR];
  __shared__ unsigned short bs[BN][LDR];

  const int tid = threadIdx.x;
  const int lane = tid & 63;
  const int wid = tid >> 6;
  constexpr int WCOLS = BN / 64;
  const int wr = wid / WCOLS;
  const int wc = wid % WCOLS;
  const int row0 = wr * 64;
  const int col0 = wc * 64;
  const int fq = lane >> 4;
  const int fr = lane & 15;
  const int brow0 = blockIdx.x * BM;

  f32x4 acc[4][4];
#pragma unroll
  for (int m = 0; m < 4; ++m)
#pragma unroll
    for (int n = 0; n < 4; ++n) acc[m][n] = (f32x4)(0.f);

  for (int k0 = 0; k0 < K; k0 += BK) {
    __syncthreads();
    for (int chunk = tid; chunk < BM * (BK / 8); chunk += NTHR) {
      int r = chunk >> 3, c = chunk & 7;
      int gr = brow0 + r;
      uint4 v = make_uint4(0u, 0u, 0u, 0u);
      if (gr < N_NODES) v = *(const uint4*)(X + (size_t)gr * K + k0 + c * 8);
      *(uint4*)&as[r][c * 8] = v;
    }
    for (int chunk = tid; chunk < BN * (BK / 8); chunk += NTHR) {
      int r = chunk >> 3, c = chunk & 7;
      *(uint4*)&bs[r][c * 8] = *(const uint4*)(Wt + (size_t)r * K + k0 + c * 8);
    }
    __syncthreads();
#pragma unroll
    for (int ks = 0; ks < 2; ++ks) {
      bf16x8 af[4], bfv[4];
#pragma unroll
      for (int m = 0; m < 4; ++m)
        af[m] = *(const bf16x8*)&as[row0 + m * 16 + fr][ks * 32 + fq * 8];
#pragma unroll
      for (int n = 0; n < 4; ++n)
        bfv[n] = *(const bf16x8*)&bs[col0 + n * 16 + fr][ks * 32 + fq * 8];
#pragma unroll
      for (int m = 0; m < 4; ++m)
#pragma unroll
        for (int n = 0; n < 4; ++n)
          acc[m][n] = __builtin_amdgcn_mfma_f32_16x16x32_bf16(af[m], bfv[n], acc[m][n], 0, 0, 0);
    }
  }

#pragma unroll
  for (int m = 0; m < 4; ++m) {
#pragma unroll
    for (int j = 0; j < 4; ++j) {
      int grow = brow0 + row0 + m * 16 + fq * 4 + j;
      if (grow < N_NODES) {
        float sc = scale[grow];
#pragma unroll
        for (int n = 0; n < 4; ++n) {
          int col = col0 + n * 16 + fr;
          out[(size_t)grow * BN + col] = f2bf(acc[m][n][j] * sc);
        }
      }
    }
  }
}

// ---------------- gather F=128 bf16: indices+scales preloaded, shfl-broadcast ----------------
// lane l preloads bidx = bucket[node*CAP+l], dsv = dsrc[bidx]; per edge j the wave
// gets (s, ds) via __shfl -- removes two dependent memory hops from the inner loop.
__global__ __launch_bounds__(256) void k_gather128(const int* __restrict__ bucket,
                                                   const unsigned* __restrict__ cnt,
                                                   const unsigned short* __restrict__ h,
                                                   const float* __restrict__ dsrc,
                                                   const float* __restrict__ ddst,
                                                   const float* __restrict__ b,
                                                   unsigned short* __restrict__ out) {
  const int lane = threadIdx.x & 63;
  const int node = blockIdx.x * 4 + (threadIdx.x >> 6);
  if (node >= N_NODES) return;
  const unsigned deg = min(cnt[node], (unsigned)CAP);
  const int* bp = bucket + (size_t)node * CAP;
  // preload: slots >= deg are unwritten (poison) -> guard to a safe index
  int bidx = (lane < (int)deg) ? bp[lane] : 0;
  float dsv = dsrc[bidx];
  const unsigned* hp = (const unsigned*)h;  // 64 uints per row
  float a0 = 0.f, a1 = 0.f;
  int j = 0;
  for (; j + 4 <= (int)deg; j += 4) {
    int s0 = __shfl(bidx, j + 0), s1 = __shfl(bidx, j + 1);
    int s2 = __shfl(bidx, j + 2), s3 = __shfl(bidx, j + 3);
    float d0 = __shfl(dsv, j + 0), d1 = __shfl(dsv, j + 1);
    float d2 = __shfl(dsv, j + 2), d3 = __shfl(dsv, j + 3);
    unsigned u0 = hp[(size_t)s0 * 64 + lane];
    unsigned u1 = hp[(size_t)s1 * 64 + lane];
    unsigned u2 = hp[(size_t)s2 * 64 + lane];
    unsigned u3 = hp[(size_t)s3 * 64 + lane];
    a0 += d0 * bflo(u0) + d1 * bflo(u1) + d2 * bflo(u2) + d3 * bflo(u3);
    a1 += d0 * bfhi(u0) + d1 * bfhi(u1) + d2 * bfhi(u2) + d3 * bfhi(u3);
  }
  for (; j < (int)deg; ++j) {
    int s = __shfl(bidx, j);
    float ds = __shfl(dsv, j);
    unsigned u = hp[(size_t)s * 64 + lane];
    a0 += ds * bflo(u);
    a1 += ds * bfhi(u);
  }
  float dd = ddst[node];
  float2 bb = *(const float2*)(b + lane * 2);
  float v0 = fmaxf(a0 * dd + bb.x, 0.f);
  float v1 = fmaxf(a1 * dd + bb.y, 0.f);
  unsigned o = (unsigned)f2bf(v0) | ((unsigned)f2bf(v1) << 16);
  ((unsigned*)out)[(size_t)node * 64 + lane] = o;
}

// ---------------- gather F=64 bf16 -> bf16: indices preloaded, shfl-broadcast ----------------
__global__ __launch_bounds__(256) void k_gather64(const int* __restrict__ bucket,
                                                  const unsigned* __restrict__ cnt,
                                                  const unsigned short* __restrict__ h,
                                                  const float* __restrict__ ddst,
                                                  const float* __restrict__ b,
                                                  unsigned short* __restrict__ out) {
  const int lane = threadIdx.x & 63;
  const int node = blockIdx.x * 4 + (threadIdx.x >> 6);
  if (node >= N_NODES) return;
  const int half = lane >> 5;
  const int fl = lane & 31;
  const unsigned deg = min(cnt[node], (unsigned)CAP);
  const int* bp = bucket + (size_t)node * CAP;
  int bidx = (lane < (int)deg) ? bp[lane] : 0;
  const unsigned* hp = (const unsigned*)h;  // 32 uints per row
  float a0 = 0.f, a1 = 0.f;
  int j = half;
  for (; j + 2 < (int)deg; j += 4) {
    int s0 = __shfl(bidx, j), s1 = __shfl(bidx, j + 2);
    unsigned u0 = hp[(size_t)s0 * 32 + fl];
    unsigned u1 = hp[(size_t)s1 * 32 + fl];
    a0 += bflo(u0) + bflo(u1);
    a1 += bfhi(u0) + bfhi(u1);
  }
  if (j < (int)deg) {
    int s = __shfl(bidx, j);
    unsigned u = hp[(size_t)s * 32 + fl];
    a0 += bflo(u);
    a1 += bfhi(u);
  }
  a0 += __shfl_xor(a0, 32);
  a1 += __shfl_xor(a1, 32);
  if (half == 0) {
    float dd = ddst[node];
    float2 bb = *(const float2*)(b + fl * 2);
    float v0 = fmaxf(a0 * dd + bb.x, 0.f);
    float v1 = fmaxf(a1 * dd + bb.y, 0.f);
    unsigned o = (unsigned)f2bf(v0) | ((unsigned)f2bf(v1) << 16);
    ((unsigned*)out)[(size_t)node * 32 + fl] = o;
  }
}

// ---------------- final (MFMA): logits = h @ Wf + bf; out = log_softmax ----------------
__global__ __launch_bounds__(256) void k_final_mfma(const unsigned short* __restrict__ h,
                                                    const unsigned short* __restrict__ Wfp,
                                                    const float* __restrict__ bf,
                                                    float* __restrict__ out) {
  constexpr int BM = 64;
  constexpr int NF = NFPAD / 16;  // 13
  constexpr int LDR = F2 + 8;     // 72
  __shared__ unsigned short as[BM][LDR];
  __shared__ unsigned short bs[NFPAD][LDR];

  const int tid = threadIdx.x;
  const int lane = tid & 63;
  const int wid = tid >> 6;
  const int fq = lane >> 4;
  const int fr = lane & 15;
  const int brow0 = blockIdx.x * BM;

  for (int chunk = tid; chunk < BM * 8; chunk += 256) {
    int r = chunk >> 3, c = chunk & 7;
    int gr = brow0 + r;
    uint4 v = make_uint4(0u, 0u, 0u, 0u);
    if (gr < N_NODES) v = *(const uint4*)(h + (size_t)gr * F2 + c * 8);
    *(uint4*)&as[r][c * 8] = v;
  }
  for (int chunk = tid; chunk < NFPAD * 8; chunk += 256) {
    int r = chunk >> 3, c = chunk & 7;
    *(uint4*)&bs[r][c * 8] = *(const uint4*)(Wfp + (size_t)r * F2 + c * 8);
  }
  __syncthreads();

  f32x4 acc[NF];
#pragma unroll
  for (int n = 0; n < NF; ++n) acc[n] = (f32x4)(0.f);

#pragma unroll
  for (int ks = 0; ks < 2; ++ks) {
    bf16x8 af = *(const bf16x8*)&as[wid * 16 + fr][ks * 32 + fq * 8];
#pragma unroll
    for (int n = 0; n < NF; ++n) {
      bf16x8 bv = *(const bf16x8*)&bs[n * 16 + fr][ks * 32 + fq * 8];
      acc[n] = __builtin_amdgcn_mfma_f32_16x16x32_bf16(af, bv, acc[n], 0, 0, 0);
    }
  }

  const int nval = (fr < NCLS - (NF - 1) * 16) ? NF : NF - 1;
  float bias[NF];
#pragma unroll
  for (int n = 0; n < NF; ++n) {
    int col = n * 16 + fr;
    bias[n] = (col < NCLS) ? bf[col] : 0.f;
  }

#pragma unroll
  for (int j = 0; j < 4; ++j) {
    const int grow = brow0 + wid * 16 + fq * 4 + j;
    float v[NF];
    float m = -1e30f;
#pragma unroll
    for (int n = 0; n < NF; ++n) {
      v[n] = acc[n][j] + bias[n];
      if (n < nval) m = fmaxf(m, v[n]);
    }
#pragma unroll
    for (int o = 1; o < 16; o <<= 1) m = fmaxf(m, __shfl_xor(m, o));
    float s = 0.f;
#pragma unroll
    for (int n = 0; n < NF; ++n)
      if (n < nval) s += expf(v[n] - m);
#pragma unroll
    for (int o = 1; o < 16; o <<= 1) s += __shfl_xor(s, o);
    float ls = logf(s);
    if (grow < N_NODES) {
#pragma unroll
      for (int n = 0; n < NF; ++n)
        if (n < nval) out[(size_t)grow * NCLS + n * 16 + fr] = v[n] - m - ls;
    }
  }
}

extern "C" void kernel_launch(void* const* d_in, const int* in_sizes, int n_in,
                              void* d_out, int out_size, void* d_ws, size_t ws_size,
                              hipStream_t stream) {
  const float* x = (const float*)d_in[0];
  const int* src = (const int*)d_in[1];
  const int* dst = (const int*)d_in[2];
  const float* W1 = (const float*)d_in[3];
  const float* b1 = (const float*)d_in[4];
  const float* W2 = (const float*)d_in[5];
  const float* b2 = (const float*)d_in[6];
  const float* Wf = (const float*)d_in[7];
  const float* bf = (const float*)d_in[8];
  float* out = (float*)d_out;

  // ---- workspace layout (~79 MB), 256B-aligned blocks ----
  char* base = (char*)d_ws;
  size_t off = 0;
  auto alloc = [&](size_t bytes) -> void* {
    off = (off + 255) & ~(size_t)255;
    void* p = base + off;
    off += bytes;
    return p;
  };
  // cs and cnt as ONE contiguous block so a single memset covers both
  unsigned* cs = (unsigned*)alloc(2 * (size_t)N_NODES * 4);
  unsigned* cnt = cs + N_NODES;
  float* dsrc = (float*)alloc(N_NODES * 4);
  float* ddst = (float*)alloc(N_NODES * 4);
  int* bucket = (int*)alloc((size_t)N_NODES * CAP * 4);                   // 25.6 MB
  unsigned short* P1 = (unsigned short*)alloc((size_t)N_NODES * F1 * 2);  // h1, then h2
  unsigned short* P2 = (unsigned short*)alloc((size_t)N_NODES * F1 * 2);  // h1f, then agg2
  unsigned short* wt1 = (unsigned short*)alloc((size_t)F1 * F0 * 2);
  unsigned short* wt2 = (unsigned short*)alloc((size_t)F2 * F1 * 2);
  unsigned short* wtf = (unsigned short*)alloc((size_t)NFPAD * F2 * 2);

  unsigned short* h1 = P1;
  unsigned short* h1f = P2;
  unsigned short* h2 = P1;             // aliases h1 (dead after gather128)
  unsigned short* agg2 = P2;           // aliases h1f (dead after gemm2)

  hipMemsetAsync(cs, 0, 2 * (size_t)N_NODES * sizeof(unsigned), stream);

  k_castw<<<(F0 * F1 + 255) / 256, 256, 0, stream>>>(W1, wt1, F0, F1);
  k_castw<<<(F1 * F2 + 255) / 256, 256, 0, stream>>>(W2, wt2, F1, F2);
  k_castwf<<<(NFPAD * F2 + 255) / 256, 256, 0, stream>>>(Wf, wtf);

  // fused: bucket-fill + layer-1 GEMM (no cross-dependency; roles interleaved)
  constexpr int NB_GEMM = (N_NODES + 127) / 128;
  constexpr int NB_FILL = 2048;
  k_fill_gemm1<<<NB_GEMM + NB_FILL, 256, 0, stream>>>(src, dst, cs, cnt, bucket, x, wt1, h1);

  k_dinv<<<(N_NODES + 255) / 256, 256, 0, stream>>>(cs, cnt, dsrc, ddst);

  // layer 1 aggregate (dsrc applied per gathered row via shfl-broadcast)
  k_gather128<<<(N_NODES + 3) / 4, 256, 0, stream>>>(bucket, cnt, h1, dsrc, ddst, b1, h1f);

  // layer 2
  k_gemm_mfma<F1, F2><<<(N_NODES + 127) / 128, 128, 0, stream>>>(h1f, wt2, dsrc, h2);
  k_gather64<<<(N_NODES + 3) / 4, 256, 0, stream>>>(bucket, cnt, h2, ddst, b2, agg2);

  // classifier + log_softmax (MFMA, in-register softmax)
  k_final_mfma<<<(N_NODES + 63) / 64, 256, 0, stream>>>(agg2, wtf, bf, out);
}